// Round 6
// baseline (5166.790 us; speedup 1.0000x reference)
//
#include <hip/hip_runtime.h>
#include <stdint.h>

#define N_ROWS 262144
#define D_DIM  1024
#define H_DIM  512
#define N_SEG  512

typedef __attribute__((ext_vector_type(4)))  float  f32x4;
typedef __attribute__((ext_vector_type(16))) float  f32x16;
typedef __attribute__((ext_vector_type(8)))  __bf16 bf16x8;
typedef __attribute__((ext_vector_type(8)))  unsigned short u16x8;

static __device__ __forceinline__ unsigned short f2bf(float f) {
  union { float f; uint32_t u; } c; c.f = f;
  return (unsigned short)((c.u + 0x7FFFu + ((c.u >> 16) & 1u)) >> 16);  // RNE
}
static __device__ __forceinline__ float fast_tanh(float u) {
  return 1.0f - 2.0f / (__expf(2.0f * u) + 1.0f);
}

// ---------------- kernel 0: repack W1,W2 f32 -> bf16, frag-major ----------
// elem idx = m*524288 + kk*8192 + col*16 + hi*8 + e  (col in [0,512), kk kstep)
__global__ void cvt_w(const float* __restrict__ W1, const float* __restrict__ W2,
                      unsigned short* __restrict__ wbf) {
  int gid = blockIdx.x * 256 + threadIdx.x;      // 0..131071 frags of 8
  int hi  = gid & 1;
  int col = (gid >> 1) & 511;
  int kk  = (gid >> 10) & 63;
  int m   = gid >> 16;
  const float* src = (m ? W2 : W1) + col * 1024 + kk * 16 + hi * 8;
  u16x8 v;
  #pragma unroll
  for (int e = 0; e < 8; ++e) v[e] = f2bf(src[e]);
  *(u16x8*)(wbf + (size_t)gid * 8) = v;
}

// ---------------- kernel 1: a[i] = (tanh(xW1^T) * softmax(xW2^T)) @ W3^T ----
// 64 rows/block, 1024 thr, 16 waves = rg(2) x cg(8); wave = 32r x 64c x 2mat.
// x staged f32 via global_load_lds (1 instr/wave/subtile), TRIPLE buffer,
// staged 2 phases ahead under counted vmcnt(32) (never drained in loop).
// Global-source swizzle (slot ^ row&15) since gload_lds dest is linear.
// W prefetched 1 kstep ahead from frag-major L2-resident copy.

#define MF(A, B, C) __builtin_amdgcn_mfma_f32_32x32x16_bf16((A), (B), (C), 0, 0, 0)

#define STAGE(T, BOFF) \
  __builtin_amdgcn_global_load_lds( \
    (const __attribute__((address_space(1))) void*)(xsrc + ((T) << 6)), \
    (__attribute__((address_space(3))) void*)(ldsw + (BOFF)), 16, 0, 0)

#define KST(BUF, KK, U0, U1, U2, U3, L0, L1, L2, L3) do { \
  L0 = *(const bf16x8*)(wbf + wf0 + (((KK) + 1) << 13)); \
  L1 = *(const bf16x8*)(wbf + wf1 + (((KK) + 1) << 13)); \
  L2 = *(const bf16x8*)(wbf + wf2 + (((KK) + 1) << 13)); \
  L3 = *(const bf16x8*)(wbf + wf3 + (((KK) + 1) << 13)); \
  const uint32_t s0_ = ((((uint32_t)(KK) & 3u) << 2) + ((uint32_t)hi << 1)) << 4; \
  f32x4 q0 = *(const f32x4*)(lds + (BUF) + abyte + (s0_ ^ axor)); \
  f32x4 q1 = *(const f32x4*)(lds + (BUF) + abyte + ((s0_ + 16u) ^ axor)); \
  bf16x8 a_; \
  a_[0]=(__bf16)q0[0]; a_[1]=(__bf16)q0[1]; a_[2]=(__bf16)q0[2]; a_[3]=(__bf16)q0[3]; \
  a_[4]=(__bf16)q1[0]; a_[5]=(__bf16)q1[1]; a_[6]=(__bf16)q1[2]; a_[7]=(__bf16)q1[3]; \
  __builtin_amdgcn_s_setprio(1); \
  au0 = MF(a_, U0, au0); \
  au1 = MF(a_, U1, au1); \
  av0 = MF(a_, U2, av0); \
  av1 = MF(a_, U3, av1); \
  __builtin_amdgcn_s_setprio(0); \
} while (0)

// phase T: stage sub T+2 (if any), compute sub T from BCUR, counted-vmcnt barrier
#define PH(T, BCUR, BSTG, DOSTG) do { \
  if (DOSTG) STAGE((T) + 2, BSTG); \
  KST(BCUR, (T)*4 + 0, WA0, WA1, WA2, WA3, WB0, WB1, WB2, WB3); \
  KST(BCUR, (T)*4 + 1, WB0, WB1, WB2, WB3, WA0, WA1, WA2, WA3); \
  KST(BCUR, (T)*4 + 2, WA0, WA1, WA2, WA3, WB0, WB1, WB2, WB3); \
  KST(BCUR, (T)*4 + 3, WB0, WB1, WB2, WB3, WA0, WA1, WA2, WA3); \
  asm volatile("s_waitcnt vmcnt(32) lgkmcnt(0)" ::: "memory"); \
  __builtin_amdgcn_s_barrier(); \
} while (0)

__launch_bounds__(1024, 4)
__global__ void alpha_kernel(const float* __restrict__ x,
                             const unsigned short* __restrict__ wbf,
                             const float* __restrict__ W3,
                             float* __restrict__ a_out)
{
  __shared__ unsigned char lds[49152 + 6144];    // 3 x 16KB f32 x-bufs + 6KB reduce
  const int tid  = threadIdx.x;
  const int lane = tid & 63;
  const int wid  = tid >> 6;                     // 0..15
  const int cgi  = wid & 7;                      // col group: 64 cols
  const int rg   = wid >> 3;                     // row group: 32 rows
  const int l31  = lane & 31;
  const int hi   = lane >> 5;
  const int row0 = blockIdx.x << 6;

  // stage mapping: subtile = 64 rows x 64 k f32 (16KB) = [row][16 slots of 16B],
  // LDS linear dest (tid*16); global source pre-swizzled: slot ^= row&15.
  const int srow  = tid >> 4;                    // 0..63
  const int sslot = (tid & 15) ^ (srow & 15);
  const float* xsrc = x + ((size_t)(row0 + srow) << 10) + (sslot << 2);
  unsigned char* ldsw = lds + ((uint32_t)(tid >> 6) << 10);  // wave slab (uniform/wave)

  // W frag element-offsets (frag-major): frag cols = cgi*64 + {l31, l31+32}
  const int c0 = (cgi << 6) + l31;
  const int c1 = c0 + 32;
  const uint32_t wf0 = (uint32_t)((c0 << 4) + (hi << 3));
  const uint32_t wf1 = (uint32_t)((c1 << 4) + (hi << 3));
  const uint32_t wf2 = wf0 + 524288u;
  const uint32_t wf3 = wf1 + 524288u;

  // A-frag read addressing (f32 rows of 256B, slot-XOR swizzle)
  const uint32_t abyte = ((uint32_t)rg << 13) + ((uint32_t)l31 << 8);
  const uint32_t axor  = ((uint32_t)(l31 & 15)) << 4;

  f32x16 au0, au1, av0, av1;
  #pragma unroll
  for (int i = 0; i < 16; ++i) { au0[i]=0.f; au1[i]=0.f; av0[i]=0.f; av1[i]=0.f; }

  // prologue: stage sub0 -> b0, sub1 -> b1; W kstep0 -> WA
  STAGE(0, 0);
  STAGE(1, 16384);
  bf16x8 WA0 = *(const bf16x8*)(wbf + wf0);
  bf16x8 WA1 = *(const bf16x8*)(wbf + wf1);
  bf16x8 WA2 = *(const bf16x8*)(wbf + wf2);
  bf16x8 WA3 = *(const bf16x8*)(wbf + wf3);
  bf16x8 WB0, WB1, WB2, WB3;
  asm volatile("s_waitcnt vmcnt(5)" ::: "memory");   // sub0 landed (5 newer ops ok)
  __builtin_amdgcn_s_barrier();

  // 16 phases, buffers rotate mod 3, stage distance 2
  PH( 0,     0, 32768, 1);
  PH( 1, 16384,     0, 1);
  PH( 2, 32768, 16384, 1);
  PH( 3,     0, 32768, 1);
  PH( 4, 16384,     0, 1);
  PH( 5, 32768, 16384, 1);
  PH( 6,     0, 32768, 1);
  PH( 7, 16384,     0, 1);
  PH( 8, 32768, 16384, 1);
  PH( 9,     0, 32768, 1);
  PH(10, 16384,     0, 1);
  PH(11, 32768, 16384, 1);
  PH(12,     0, 32768, 1);
  PH(13, 16384,     0, 1);
  PH(14, 32768,     0, 0);
  PH(15,     0,     0, 0);

  // ---- epilogue ----
  // C/D map (m74/m101): col = lane&31, row = (reg&3) + 8*(reg>>2) + 4*(lane>>5);
  // wave rows = rg*32 + row.
  float w3a = W3[c0];
  float w3b = W3[c1];
  float* redm = (float*)(lds + 49152);           // [8 cg][64 rows]
  float* reds = redm + 512;
  float* redn = redm + 1024;

  {
    float m_[16], s_[16], n_[16];
    #pragma unroll
    for (int r = 0; r < 16; ++r) m_[r] = fmaxf(av0[r], av1[r]);
    #pragma unroll
    for (int d = 1; d < 32; d <<= 1)
      #pragma unroll
      for (int r = 0; r < 16; ++r) m_[r] = fmaxf(m_[r], __shfl_xor(m_[r], d));
    #pragma unroll
    for (int r = 0; r < 16; ++r) {
      float p0 = __expf(av0[r] - m_[r]);
      float p1 = __expf(av1[r] - m_[r]);
      s_[r] = p0 + p1;
      n_[r] = fast_tanh(au0[r]) * p0 * w3a + fast_tanh(au1[r]) * p1 * w3b;
    }
    #pragma unroll
    for (int d = 1; d < 32; d <<= 1)
      #pragma unroll
      for (int r = 0; r < 16; ++r) { s_[r] += __shfl_xor(s_[r], d); n_[r] += __shfl_xor(n_[r], d); }
    if (l31 == 0) {
      #pragma unroll
      for (int r = 0; r < 16; ++r) {
        int row = (rg << 5) + (r & 3) + ((r >> 2) << 3) + (hi << 2);
        redm[(cgi << 6) + row] = m_[r];
        reds[(cgi << 6) + row] = s_[r];
        redn[(cgi << 6) + row] = n_[r];
      }
    }
  }
  __syncthreads();
  if (tid < 64) {
    float m = redm[tid];
    #pragma unroll
    for (int c = 1; c < 8; ++c) m = fmaxf(m, redm[(c << 6) + tid]);
    float s = 0.f, n = 0.f;
    #pragma unroll
    for (int c = 0; c < 8; ++c) {
      float sc2 = __expf(redm[(c << 6) + tid] - m);
      s += reds[(c << 6) + tid] * sc2;
      n += redn[(c << 6) + tid] * sc2;
    }
    a_out[row0 + tid] = n / s;
  }
}

// ---------------- kernel 2: segment softmax weights ----------------
static __device__ __forceinline__ int lower_bound(const int* __restrict__ batch, int key) {
  int lo = 0, hi = N_ROWS;
  while (lo < hi) { int mid = (lo + hi) >> 1; if (batch[mid] < key) lo = mid + 1; else hi = mid; }
  return lo;
}

__global__ void seg_kernel(const float* __restrict__ a, const int* __restrict__ batch,
                           float* __restrict__ w) {
  __shared__ float sm[8];
  int b = blockIdx.x;
  int start = lower_bound(batch, b);
  int end   = lower_bound(batch, b + 1);
  int tid = threadIdx.x;

  float m = -3.4e38f;
  for (int i = start + tid; i < end; i += 256) m = fmaxf(m, a[i]);
  for (int d = 1; d < 64; d <<= 1) m = fmaxf(m, __shfl_xor(m, d));
  if ((tid & 63) == 0) sm[tid >> 6] = m;
  __syncthreads();
  m = fmaxf(fmaxf(sm[0], sm[1]), fmaxf(sm[2], sm[3]));

  float s = 0.f;
  for (int i = start + tid; i < end; i += 256) s += __expf(a[i] - m);
  for (int d = 1; d < 64; d <<= 1) s += __shfl_xor(s, d);
  if ((tid & 63) == 0) sm[4 + (tid >> 6)] = s;
  __syncthreads();
  s = sm[4] + sm[5] + sm[6] + sm[7];

  float rinv = 1.0f / s;
  for (int i = start + tid; i < end; i += 256) w[i] = __expf(a[i] - m) * rinv;
}

// ---------------- kernel 3: z[b] = sum_i w_i * x_i ----------------
__global__ void z_kernel(const float* __restrict__ x, const float* __restrict__ w,
                         const int* __restrict__ batch, float* __restrict__ z) {
  int b = blockIdx.x >> 2, part = blockIdx.x & 3;
  int start = lower_bound(batch, b);
  int end   = lower_bound(batch, b + 1);
  int len = end - start;
  int ps = start + ((len * part) >> 2);
  int pe = start + ((len * (part + 1)) >> 2);
  int col = threadIdx.x << 2;

  f32x4 acc = (f32x4){0.f, 0.f, 0.f, 0.f};
  for (int i = ps; i < pe; ++i) {
    f32x4 xv = *(const f32x4*)(x + ((size_t)i << 10) + col);
    float wi = w[i];
    acc += xv * wi;
  }
  float* zp = z + ((size_t)b << 10) + col;
  atomicAdd(zp + 0, acc[0]);
  atomicAdd(zp + 1, acc[1]);
  atomicAdd(zp + 2, acc[2]);
  atomicAdd(zp + 3, acc[3]);
}

// ---------------- launch ----------------
extern "C" void kernel_launch(void* const* d_in, const int* in_sizes, int n_in,
                              void* d_out, int out_size, void* d_ws, size_t ws_size,
                              hipStream_t stream) {
  const float* x     = (const float*)d_in[0];
  const int*   batch = (const int*)d_in[1];
  const float* W1    = (const float*)d_in[2];
  const float* W2    = (const float*)d_in[3];
  const float* W3    = (const float*)d_in[4];
  float* z = (float*)d_out;

  // ws layout: [0,2MB) W1|W2 bf16 frag-major ; [2MB,3MB) a[N] f32 ; [3MB,4MB) w[N] f32
  unsigned short* wbf = (unsigned short*)d_ws;
  float* a = (float*)((char*)d_ws + (2u << 20));
  float* w = (float*)((char*)d_ws + (3u << 20));

  (void)hipMemsetAsync(d_out, 0, (size_t)N_SEG * D_DIM * sizeof(float), stream);

  cvt_w<<<512, 256, 0, stream>>>(W1, W2, wbf);

  alpha_kernel<<<N_ROWS / 64, 1024, 0, stream>>>(x, wbf, W3, a);

  seg_kernel<<<N_SEG, 256, 0, stream>>>(a, batch, w);

  z_kernel<<<N_SEG * 4, 256, 0, stream>>>(x, w, batch, z);
}

// Round 7
// 1011.198 us; speedup vs baseline: 5.1096x; 5.1096x over previous
//
#include <hip/hip_runtime.h>
#include <stdint.h>

#define N_ROWS 262144
#define D_DIM  1024
#define H_DIM  512
#define N_SEG  512

typedef __attribute__((ext_vector_type(4)))  float  f32x4;
typedef __attribute__((ext_vector_type(16))) float  f32x16;
typedef __attribute__((ext_vector_type(8)))  __bf16 bf16x8;
typedef __attribute__((ext_vector_type(4)))  unsigned short u16x4;
typedef __attribute__((ext_vector_type(8)))  unsigned short u16x8;

static __device__ __forceinline__ unsigned short f2bf(float f) {
  union { float f; uint32_t u; } c; c.f = f;
  return (unsigned short)((c.u + 0x7FFFu + ((c.u >> 16) & 1u)) >> 16);  // RNE
}
static __device__ __forceinline__ float fast_tanh(float u) {
  return 1.0f - 2.0f / (__expf(2.0f * u) + 1.0f);
}

// ---------------- kernel 0: repack W1,W2 f32 -> bf16, frag-major ----------
// elem idx = m*524288 + kk*8192 + col*16 + hi*8 + e  (col in [0,512), kk kstep)
__global__ void cvt_w(const float* __restrict__ W1, const float* __restrict__ W2,
                      unsigned short* __restrict__ wbf) {
  int gid = blockIdx.x * 256 + threadIdx.x;      // 0..131071 frags of 8
  int hi  = gid & 1;
  int col = (gid >> 1) & 511;
  int kk  = (gid >> 10) & 63;
  int m   = gid >> 16;
  const float* src = (m ? W2 : W1) + col * 1024 + kk * 16 + hi * 8;
  u16x8 v;
  #pragma unroll
  for (int e = 0; e < 8; ++e) v[e] = f2bf(src[e]);
  *(u16x8*)(wbf + (size_t)gid * 8) = v;
}

// ---------------- kernel 1: a[i] = (tanh(xW1^T) * softmax(xW2^T)) @ W3^T ----
// 32 rows/block, 512 thr, 8 waves; wave = 32r x 64c x 2mat (acc 64/thr).
// Small LDS (11 KB) -> 2 independent blocks/CU resident: cross-block overlap
// covers barrier + W-L2-latency stalls (R5 was 1 big lockstep block).
// K in 16 subtiles of 64, dbuf 4KB LDS, x-loads 2 phases deep in regs,
// W prefetched 1 kstep ahead from frag-major L2 copy. lgkm-only barriers.
#define ENDBAR() do { \
  asm volatile("s_waitcnt lgkmcnt(0)" ::: "memory"); \
  __builtin_amdgcn_s_barrier(); \
} while (0)

#define MF(A, B, C) __builtin_amdgcn_mfma_f32_32x32x16_bf16((A), (B), (C), 0, 0, 0)

#define KST(BUFOFF, KK, U0, U1, U2, U3, L0, L1, L2, L3) do { \
  L0 = *(const bf16x8*)(wbf + wf0 + (((KK) + 1) << 13)); \
  L1 = *(const bf16x8*)(wbf + wf1 + (((KK) + 1) << 13)); \
  L2 = *(const bf16x8*)(wbf + wf2 + (((KK) + 1) << 13)); \
  L3 = *(const bf16x8*)(wbf + wf3 + (((KK) + 1) << 13)); \
  bf16x8 a_ = *(const bf16x8*)(lds + (BUFOFF) + ((ra0 + (((KK) & 3) << 5)) ^ swz)); \
  __builtin_amdgcn_s_setprio(1); \
  au0 = MF(a_, U0, au0); \
  au1 = MF(a_, U1, au1); \
  av0 = MF(a_, U2, av0); \
  av1 = MF(a_, U3, av1); \
  __builtin_amdgcn_s_setprio(0); \
} while (0)

#define PACK4(DSTBYTE, Q) do { \
  u16x4 _v; _v[0]=f2bf(Q[0]); _v[1]=f2bf(Q[1]); _v[2]=f2bf(Q[2]); _v[3]=f2bf(Q[3]); \
  *(u16x4*)(lds + (DSTBYTE)) = _v; \
} while (0)

__launch_bounds__(512, 4)
__global__ void alpha_kernel(const float* __restrict__ x,
                             const unsigned short* __restrict__ wbf,
                             const float* __restrict__ W3,
                             float* __restrict__ a_out)
{
  __shared__ unsigned char lds[8192 + 3072];     // 2 x 4KB x-bufs + 3KB reduce
  const int tid  = threadIdx.x;
  const int lane = tid & 63;
  const int cgi  = tid >> 6;                     // wave = col group: 64 cols
  const int l31  = lane & 31;
  const int hi   = lane >> 5;
  const int row0 = blockIdx.x << 5;

  // staging: subtile = 32 rows x 64 k (bf16, 4KB). thread -> row sr, 4-float chunk sc
  const int sr = tid >> 4;                       // 0..31
  const int sc = tid & 15;                       // 0..15
  const float* xptr = x + ((size_t)(row0 + sr) << 10) + (sc << 2);
  const uint32_t wbyte = ((uint32_t)((sr << 7) + (sc << 3))) ^ (((uint32_t)(sr & 7)) << 4);

  // W frag element-offsets (frag-major layout): frag cols = cgi*64 + {l31, l31+32}
  const int c0 = (cgi << 6) + l31;
  const int c1 = c0 + 32;
  const uint32_t wf0 = (uint32_t)((c0 << 4) + (hi << 3));            // W1 frag0
  const uint32_t wf1 = (uint32_t)((c1 << 4) + (hi << 3));            // W1 frag1
  const uint32_t wf2 = wf0 + 524288u;                                 // W2 frag0
  const uint32_t wf3 = wf1 + 524288u;                                 // W2 frag1

  f32x16 au0, au1, av0, av1;
  #pragma unroll
  for (int i = 0; i < 16; ++i) { au0[i]=0.f; au1[i]=0.f; av0[i]=0.f; av1[i]=0.f; }

  const uint32_t swz = (((uint32_t)(l31 & 7)) << 4);
  const uint32_t ra0 = (((uint32_t)l31) << 7) + (((uint32_t)hi) << 4);

  // prologue: sub0 -> buf0; sub1 -> regs; W kstep0 -> WA*
  f32x4 xa = *(const f32x4*)xptr;
  f32x4 xb = *(const f32x4*)(xptr + 64);
  PACK4(wbyte, xa);
  bf16x8 WA0 = *(const bf16x8*)(wbf + wf0);
  bf16x8 WA1 = *(const bf16x8*)(wbf + wf1);
  bf16x8 WA2 = *(const bf16x8*)(wbf + wf2);
  bf16x8 WA3 = *(const bf16x8*)(wbf + wf3);
  bf16x8 WB0, WB1, WB2, WB3;
  ENDBAR();

  #pragma unroll 1
  for (int t = 0; t < 16; t += 2) {
    // even phase: compute buf0 (sub t); pack sub t+1 -> buf1; load sub t+2 -> xa
    if (t + 2 < 16) xa = *(const f32x4*)(xptr + ((t + 2) << 6));
    PACK4(4096 + wbyte, xb);
    KST(0, t * 4 + 0, WA0, WA1, WA2, WA3, WB0, WB1, WB2, WB3);
    KST(0, t * 4 + 1, WB0, WB1, WB2, WB3, WA0, WA1, WA2, WA3);
    KST(0, t * 4 + 2, WA0, WA1, WA2, WA3, WB0, WB1, WB2, WB3);
    KST(0, t * 4 + 3, WB0, WB1, WB2, WB3, WA0, WA1, WA2, WA3);
    ENDBAR();
    // odd phase: compute buf1 (sub t+1); pack sub t+2 -> buf0; load sub t+3 -> xb
    if (t + 3 < 16) xb = *(const f32x4*)(xptr + ((t + 3) << 6));
    if (t + 2 < 16) PACK4(wbyte, xa);
    KST(4096, t * 4 + 4, WA0, WA1, WA2, WA3, WB0, WB1, WB2, WB3);
    KST(4096, t * 4 + 5, WB0, WB1, WB2, WB3, WA0, WA1, WA2, WA3);
    KST(4096, t * 4 + 6, WA0, WA1, WA2, WA3, WB0, WB1, WB2, WB3);
    KST(4096, t * 4 + 7, WB0, WB1, WB2, WB3, WA0, WA1, WA2, WA3);
    ENDBAR();
  }

  // ---- epilogue ----
  // C/D map (m74/m101): col = lane&31, row = (reg&3) + 8*(reg>>2) + 4*(lane>>5).
  float w3a = W3[c0];
  float w3b = W3[c1];
  float* redm = (float*)(lds + 8192);            // [8 cg][32 rows]
  float* reds = redm + 256;
  float* redn = redm + 512;

  {
    float m_[16], s_[16], n_[16];
    #pragma unroll
    for (int r = 0; r < 16; ++r) m_[r] = fmaxf(av0[r], av1[r]);
    #pragma unroll
    for (int d = 1; d < 32; d <<= 1)
      #pragma unroll
      for (int r = 0; r < 16; ++r) m_[r] = fmaxf(m_[r], __shfl_xor(m_[r], d));
    #pragma unroll
    for (int r = 0; r < 16; ++r) {
      float p0 = __expf(av0[r] - m_[r]);
      float p1 = __expf(av1[r] - m_[r]);
      s_[r] = p0 + p1;
      n_[r] = fast_tanh(au0[r]) * p0 * w3a + fast_tanh(au1[r]) * p1 * w3b;
    }
    #pragma unroll
    for (int d = 1; d < 32; d <<= 1)
      #pragma unroll
      for (int r = 0; r < 16; ++r) { s_[r] += __shfl_xor(s_[r], d); n_[r] += __shfl_xor(n_[r], d); }
    if (l31 == 0) {
      #pragma unroll
      for (int r = 0; r < 16; ++r) {
        int row = (r & 3) + ((r >> 2) << 3) + (hi << 2);
        redm[(cgi << 5) + row] = m_[r];
        reds[(cgi << 5) + row] = s_[r];
        redn[(cgi << 5) + row] = n_[r];
      }
    }
  }
  __syncthreads();
  if (tid < 32) {
    float m = redm[tid];
    #pragma unroll
    for (int c = 1; c < 8; ++c) m = fmaxf(m, redm[(c << 5) + tid]);
    float s = 0.f, n = 0.f;
    #pragma unroll
    for (int c = 0; c < 8; ++c) {
      float sc2 = __expf(redm[(c << 5) + tid] - m);
      s += reds[(c << 5) + tid] * sc2;
      n += redn[(c << 5) + tid] * sc2;
    }
    a_out[row0 + tid] = n / s;
  }
}

// ---------------- kernel 2: segment softmax weights ----------------
static __device__ __forceinline__ int lower_bound(const int* __restrict__ batch, int key) {
  int lo = 0, hi = N_ROWS;
  while (lo < hi) { int mid = (lo + hi) >> 1; if (batch[mid] < key) lo = mid + 1; else hi = mid; }
  return lo;
}

__global__ void seg_kernel(const float* __restrict__ a, const int* __restrict__ batch,
                           float* __restrict__ w) {
  __shared__ float sm[8];
  int b = blockIdx.x;
  int start = lower_bound(batch, b);
  int end   = lower_bound(batch, b + 1);
  int tid = threadIdx.x;

  float m = -3.4e38f;
  for (int i = start + tid; i < end; i += 256) m = fmaxf(m, a[i]);
  for (int d = 1; d < 64; d <<= 1) m = fmaxf(m, __shfl_xor(m, d));
  if ((tid & 63) == 0) sm[tid >> 6] = m;
  __syncthreads();
  m = fmaxf(fmaxf(sm[0], sm[1]), fmaxf(sm[2], sm[3]));

  float s = 0.f;
  for (int i = start + tid; i < end; i += 256) s += __expf(a[i] - m);
  for (int d = 1; d < 64; d <<= 1) s += __shfl_xor(s, d);
  if ((tid & 63) == 0) sm[4 + (tid >> 6)] = s;
  __syncthreads();
  s = sm[4] + sm[5] + sm[6] + sm[7];

  float rinv = 1.0f / s;
  for (int i = start + tid; i < end; i += 256) w[i] = __expf(a[i] - m) * rinv;
}

// ---------------- kernel 3: z[b] = sum_i w_i * x_i ----------------
__global__ void z_kernel(const float* __restrict__ x, const float* __restrict__ w,
                         const int* __restrict__ batch, float* __restrict__ z) {
  int b = blockIdx.x >> 2, part = blockIdx.x & 3;
  int start = lower_bound(batch, b);
  int end   = lower_bound(batch, b + 1);
  int len = end - start;
  int ps = start + ((len * part) >> 2);
  int pe = start + ((len * (part + 1)) >> 2);
  int col = threadIdx.x << 2;

  f32x4 acc = (f32x4){0.f, 0.f, 0.f, 0.f};
  for (int i = ps; i < pe; ++i) {
    f32x4 xv = *(const f32x4*)(x + ((size_t)i << 10) + col);
    float wi = w[i];
    acc += xv * wi;
  }
  float* zp = z + ((size_t)b << 10) + col;
  atomicAdd(zp + 0, acc[0]);
  atomicAdd(zp + 1, acc[1]);
  atomicAdd(zp + 2, acc[2]);
  atomicAdd(zp + 3, acc[3]);
}

// ---------------- launch ----------------
extern "C" void kernel_launch(void* const* d_in, const int* in_sizes, int n_in,
                              void* d_out, int out_size, void* d_ws, size_t ws_size,
                              hipStream_t stream) {
  const float* x     = (const float*)d_in[0];
  const int*   batch = (const int*)d_in[1];
  const float* W1    = (const float*)d_in[2];
  const float* W2    = (const float*)d_in[3];
  const float* W3    = (const float*)d_in[4];
  float* z = (float*)d_out;

  // ws layout: [0,2MB) W1|W2 bf16 frag-major ; [2MB,3MB) a[N] f32 ; [3MB,4MB) w[N] f32
  unsigned short* wbf = (unsigned short*)d_ws;
  float* a = (float*)((char*)d_ws + (2u << 20));
  float* w = (float*)((char*)d_ws + (3u << 20));

  (void)hipMemsetAsync(d_out, 0, (size_t)N_SEG * D_DIM * sizeof(float), stream);

  cvt_w<<<512, 256, 0, stream>>>(W1, W2, wbf);

  alpha_kernel<<<N_ROWS / 32, 512, 0, stream>>>(x, wbf, W3, a);

  seg_kernel<<<N_SEG, 256, 0, stream>>>(a, batch, w);

  z_kernel<<<N_SEG * 4, 256, 0, stream>>>(x, w, batch, z);
}